// Round 1
// baseline (1249.184 us; speedup 1.0000x reference)
//
#include <hip/hip_runtime.h>

// FrequencyBandModulation: x[8,256,128,128] f32, W[3,1,256,3,3], B[3,1]
// out = g1*x + (g2-g1)*low1 + (g3-g2)*low2 + (1-g3)*low3
//   low_k = irfft2(rfft2(x)*mask_k) with mask_k = (i<n_k || i>=64) && (j<n_k),
//   n_k = 64/freq, freq in {2,4,8};  g_k = 2*sigmoid(conv3x3_{256->1}(x)+B_k)
// Exact pocketfft c2r semantics: Im of width DC bin dropped; width Nyquist masked out.

#define NPIX 16384
#define NCHN 256
constexpr float STEP = 6.283185307179586476925f / 128.f;  // 2*pi/128

// ---------------- Kernel G: gate coefficient planes into d_ws ----------------
// coef[0]=g1, coef[1]=g2-g1, coef[2]=g3-g2, coef[3]=1-g3  (each [8][128][128])
__global__ __launch_bounds__(256) void gates_kernel(
    const float* __restrict__ x, const float* __restrict__ Wg,
    const float* __restrict__ Bg, float* __restrict__ coef) {
  int blk = blockIdx.x;
  int b = blk >> 6;
  int tile = blk & 63;
  int m = ((tile >> 3) << 4) + (threadIdx.x >> 4);
  int n = ((tile & 7) << 4) + (threadIdx.x & 15);
  float a0 = 0.f, a1 = 0.f, a2 = 0.f;
  const float* xb = x + (size_t)b * NCHN * NPIX;
  for (int c = 0; c < NCHN; ++c) {
    const float* xc = xb + (size_t)c * NPIX;
    const float* wc = Wg + c * 9;  // W[k][0][c][kh][kw] -> k*2304 + c*9 + tap
    #pragma unroll
    for (int dh = -1; dh <= 1; ++dh) {
      int gm = m + dh;
      bool vm = (unsigned)gm < 128u;
      #pragma unroll
      for (int dw = -1; dw <= 1; ++dw) {
        int gn = n + dw;
        float xv = (vm && (unsigned)gn < 128u) ? xc[gm * 128 + gn] : 0.f;
        int tap = (dh + 1) * 3 + (dw + 1);
        a0 = fmaf(xv, wc[tap], a0);
        a1 = fmaf(xv, wc[2304 + tap], a1);
        a2 = fmaf(xv, wc[4608 + tap], a2);
      }
    }
  }
  a0 += Bg[0]; a1 += Bg[1]; a2 += Bg[2];
  float g1 = 2.f / (1.f + expf(-a0));
  float g2 = 2.f / (1.f + expf(-a1));
  float g3 = 2.f / (1.f + expf(-a2));
  int pix = b * NPIX + m * 128 + n;
  coef[pix]              = g1;
  coef[131072 + pix]     = g2 - g1;
  coef[262144 + pix]     = g3 - g2;
  coef[393216 + pix]     = 1.f - g3;
}

// ---------------- Stage C: masked inverse height transform ----------------
// V[m][j] = sum_{rows r in S_k} (DR+i*DI)[r][j] * e^{+i*2pi*i(r)*m/128}
//   rows: r=0..nk-1 (i=r) and r=32..95 (i=r+32, i.e. 64..127)
template <int NM, int NJ>
__device__ __forceinline__ void stage_C(
    const int* mv, int j0, int nk,
    const float (*dr)[33], const float (*di)[33],
    float (*vr)[33], float (*vi)[33]) {
  float cm[NM], sm[NM], c[NM], s[NM];
  float aR[NM][NJ], aI[NM][NJ];
  #pragma unroll
  for (int u = 0; u < NM; ++u) {
    cm[u] = cosf(STEP * (float)mv[u]);
    sm[u] = sinf(STEP * (float)mv[u]);
    c[u] = 1.f; s[u] = 0.f;
    #pragma unroll
    for (int jj = 0; jj < NJ; ++jj) { aR[u][jj] = 0.f; aI[u][jj] = 0.f; }
  }
  for (int r = 0; r < nk; ++r) {              // segment 1: i = r, start angle 0
    float rv[NJ], iv[NJ];
    #pragma unroll
    for (int jj = 0; jj < NJ; ++jj) { rv[jj] = dr[r][j0 + jj]; iv[jj] = di[r][j0 + jj]; }
    #pragma unroll
    for (int u = 0; u < NM; ++u) {
      #pragma unroll
      for (int jj = 0; jj < NJ; ++jj) {
        aR[u][jj] += rv[jj] * c[u] - iv[jj] * s[u];
        aI[u][jj] += rv[jj] * s[u] + iv[jj] * c[u];
      }
      float cn = c[u] * cm[u] - s[u] * sm[u];
      s[u] = s[u] * cm[u] + c[u] * sm[u];
      c[u] = cn;
    }
  }
  #pragma unroll
  for (int u = 0; u < NM; ++u) {              // segment 2 init: i=64 -> cos(pi*m)=+/-1 exactly
    c[u] = (mv[u] & 1) ? -1.f : 1.f; s[u] = 0.f;
  }
  for (int r = 32; r < 96; ++r) {             // segment 2: i = r+32 in [64,127]
    float rv[NJ], iv[NJ];
    #pragma unroll
    for (int jj = 0; jj < NJ; ++jj) { rv[jj] = dr[r][j0 + jj]; iv[jj] = di[r][j0 + jj]; }
    #pragma unroll
    for (int u = 0; u < NM; ++u) {
      #pragma unroll
      for (int jj = 0; jj < NJ; ++jj) {
        aR[u][jj] += rv[jj] * c[u] - iv[jj] * s[u];
        aI[u][jj] += rv[jj] * s[u] + iv[jj] * c[u];
      }
      float cn = c[u] * cm[u] - s[u] * sm[u];
      s[u] = s[u] * cm[u] + c[u] * sm[u];
      c[u] = cn;
    }
  }
  #pragma unroll
  for (int u = 0; u < NM; ++u)
    #pragma unroll
    for (int jj = 0; jj < NJ; ++jj) {
      vr[mv[u]][j0 + jj] = aR[u][jj];
      vi[mv[u]][j0 + jj] = aI[u][jj];
    }
}

// ---------------- Stage D: inverse width transform + gated fold ----------------
// low[m,n] = (1/16384)*( VR[m,0] + 2*sum_{j=1}^{NKJ-1} (VR[m,j]cos(2pi j n/128) - VI[m,j]sin(...)) )
// oacc[nn] += coef[k][pix] * low[m, n0+nn]
template <int NKJ>
__device__ __forceinline__ void stage_D(
    int m, int frac, const float (*vr)[33], const float (*vi)[33],
    const float* __restrict__ cof, float* oacc) {
  float lacc[32];
  float rv0 = vr[m][0];
  #pragma unroll
  for (int nn = 0; nn < 32; ++nn) lacc[nn] = rv0;
  const float c1 = cosf(STEP), s1 = sinf(STEP);
  float cb = c1, sb = s1;                      // cos/sin(2pi j/128), starts at j=1
  for (int j = 1; j < NKJ; ++j) {
    float rv = 2.f * vr[m][j], iv = 2.f * vi[m][j];
    int q4 = (j * frac) & 3;                   // start angle j*n0*2pi/128 = (pi/2)*j*frac: exact
    float c = (q4 == 0) ? 1.f : ((q4 == 2) ? -1.f : 0.f);
    float s = (q4 == 1) ? 1.f : ((q4 == 3) ? -1.f : 0.f);
    #pragma unroll
    for (int nn = 0; nn < 32; ++nn) {
      lacc[nn] += rv * c - iv * s;
      float cn = c * cb - s * sb;
      s = s * cb + c * sb;
      c = cn;
    }
    float cbn = cb * c1 - sb * s1;             // advance step const to j+1
    sb = sb * c1 + cb * s1;
    cb = cbn;
  }
  #pragma unroll
  for (int nn = 0; nn < 32; ++nn)
    oacc[nn] = fmaf(cof[nn], lacc[nn] * (1.f / 16384.f), oacc[nn]);
}

// ---------------- Kernel F: per-image truncated spectral pipeline ----------------
__global__ __launch_bounds__(512) void freq_kernel(
    const float* __restrict__ x, const float* __restrict__ coef,
    float* __restrict__ out) {
  __shared__ float xs[128][129];               // padded: conflict-free strided reads
  __shared__ float cr[128][33], ci[128][33];   // width-DFT coeffs; reused as VR/VI
  __shared__ float dr[96][33], di[96][33];     // height-DFT on the 96 surviving rows
  int t = threadIdx.x;
  int img = blockIdx.x;                        // b*256 + c
  const float* xg = x + (size_t)img * NPIX;

  // load image (coalesced float4)
  #pragma unroll
  for (int i = 0; i < 8; ++i) {
    int f = t + i * 512;
    int row = f >> 5, c4 = (f & 31) << 2;
    float4 v = reinterpret_cast<const float4*>(xg)[f];
    xs[row][c4] = v.x; xs[row][c4 + 1] = v.y; xs[row][c4 + 2] = v.z; xs[row][c4 + 3] = v.w;
  }
  __syncthreads();

  // Stage A: width DFT, j<32:  CR[p][j] = sum_q x[p][q] cos(2pi j q/128), CI = -sum sin
  {
    int l = t & 31;
    int j0 = (t >> 5) << 1;                    // 0,2,...,30
    float cb[2], sb[2], c[2] = {1.f, 1.f}, s[2] = {0.f, 0.f};
    cb[0] = cosf(STEP * (float)j0);       sb[0] = sinf(STEP * (float)j0);
    cb[1] = cosf(STEP * (float)(j0 + 1)); sb[1] = sinf(STEP * (float)(j0 + 1));
    float aR[4][2] = {}, aI[4][2] = {};
    for (int q = 0; q < 128; ++q) {
      float xv[4];
      #pragma unroll
      for (int u = 0; u < 4; ++u) xv[u] = xs[l + 32 * u][q];
      #pragma unroll
      for (int jj = 0; jj < 2; ++jj) {
        #pragma unroll
        for (int u = 0; u < 4; ++u) {
          aR[u][jj] += xv[u] * c[jj];
          aI[u][jj] -= xv[u] * s[jj];
        }
        float cn = c[jj] * cb[jj] - s[jj] * sb[jj];
        s[jj] = s[jj] * cb[jj] + c[jj] * sb[jj];
        c[jj] = cn;
      }
    }
    #pragma unroll
    for (int u = 0; u < 4; ++u)
      #pragma unroll
      for (int jj = 0; jj < 2; ++jj) {
        cr[l + 32 * u][j0 + jj] = aR[u][jj];
        ci[l + 32 * u][j0 + jj] = aI[u][jj];
      }
  }
  __syncthreads();

  // Stage B: height DFT on surviving rows: D[r][j] = sum_p (CR+iCI)[p][j] e^{-i 2pi i(r) p/128}
  {
    int ig = t & 31;
    int j0 = (t >> 5) << 1;
    int ifr[3] = { ig, ig + 64, ig + 96 };     // freqs for D-rows ig, ig+32, ig+64
    int rw[3]  = { ig, ig + 32, ig + 64 };
    float cm[3], sm[3], c[3] = {1.f, 1.f, 1.f}, s[3] = {0.f, 0.f, 0.f};
    #pragma unroll
    for (int u = 0; u < 3; ++u) { cm[u] = cosf(STEP * (float)ifr[u]); sm[u] = sinf(STEP * (float)ifr[u]); }
    float aR[3][2] = {}, aI[3][2] = {};
    for (int p = 0; p < 128; ++p) {
      float rv[2] = { cr[p][j0], cr[p][j0 + 1] };
      float iv[2] = { ci[p][j0], ci[p][j0 + 1] };
      #pragma unroll
      for (int u = 0; u < 3; ++u) {
        #pragma unroll
        for (int jj = 0; jj < 2; ++jj) {
          aR[u][jj] += rv[jj] * c[u] + iv[jj] * s[u];   // Re[(CR+iCI)e^{-i t}]
          aI[u][jj] += iv[jj] * c[u] - rv[jj] * s[u];   // Im[...]
        }
        float cn = c[u] * cm[u] - s[u] * sm[u];
        s[u] = s[u] * cm[u] + c[u] * sm[u];
        c[u] = cn;
      }
    }
    #pragma unroll
    for (int u = 0; u < 3; ++u)
      #pragma unroll
      for (int jj = 0; jj < 2; ++jj) {
        dr[rw[u]][j0 + jj] = aR[u][jj];
        di[rw[u]][j0 + jj] = aI[u][jj];
      }
  }
  __syncthreads();

  // Output accumulator: start with g1 * x
  int m = t >> 2;
  int n0 = (t & 3) << 5;
  int frac = t & 3;
  const float* cof = coef + (size_t)(img >> 8) * NPIX + m * 128 + n0;
  float oacc[32];
  #pragma unroll
  for (int nn = 0; nn < 32; ++nn) oacc[nn] = cof[nn] * xs[m][n0 + nn];

  // ---- k = 1 (n_k = 32) ----
  {
    int l = t & 31; int mv[4] = { l, l + 32, l + 64, l + 96 };
    stage_C<4, 2>(mv, (t >> 5) << 1, 32, dr, di, cr, ci);
  }
  __syncthreads();
  stage_D<32>(m, frac, cr, ci, cof + 131072, oacc);
  __syncthreads();

  // ---- k = 2 (n_k = 16) ----
  {
    int l = t & 31; int mv[4] = { l, l + 32, l + 64, l + 96 };
    stage_C<4, 1>(mv, t >> 5, 16, dr, di, cr, ci);
  }
  __syncthreads();
  stage_D<16>(m, frac, cr, ci, cof + 262144, oacc);
  __syncthreads();

  // ---- k = 3 (n_k = 8) ----
  {
    int l = t & 63; int mv[2] = { l, l + 64 };
    stage_C<2, 1>(mv, t >> 6, 8, dr, di, cr, ci);
  }
  __syncthreads();
  stage_D<8>(m, frac, cr, ci, cof + 393216, oacc);

  float* op = out + (size_t)img * NPIX + m * 128 + n0;
  #pragma unroll
  for (int nn = 0; nn < 32; ++nn) op[nn] = oacc[nn];
}

extern "C" void kernel_launch(void* const* d_in, const int* in_sizes, int n_in,
                              void* d_out, int out_size, void* d_ws, size_t ws_size,
                              hipStream_t stream) {
  const float* x  = (const float*)d_in[0];
  const float* Wg = (const float*)d_in[1];
  const float* Bg = (const float*)d_in[2];
  float* out  = (float*)d_out;
  float* coef = (float*)d_ws;   // needs 4*8*16384*4 = 2 MiB of workspace
  gates_kernel<<<512, 256, 0, stream>>>(x, Wg, Bg, coef);
  freq_kernel<<<2048, 512, 0, stream>>>(x, coef, out);
}

// Round 2
// 714.314 us; speedup vs baseline: 1.7488x; 1.7488x over previous
//
#include <hip/hip_runtime.h>

// FrequencyBandModulation via separable circulant form:
//   low_k = KR_k (X Qc_k) + KI_k (X Qs_k)      (all 128x128 constant matrices, bf16 MFMA)
//   out   = g1*x + (g2-g1)low_1 + (g3-g2)low_2 + (1-g3)low_3
// Qc/Qs[q][n] = (1/128) sum_{j<nk} w_j cos/sin(2pi j (q-n)/128), w_0=1 else 2
// KR/KI[m][p] = (1/128) sum_{i in S_k} cos/sin(2pi i (m-p)/128), S_k = [0,nk) U [64,128)
// (KI term carries the asymmetric-row-mask + c2r Im-drop semantics; matches round-1 verified math)

#define NPIX 16384
#define NCHN 256

typedef __attribute__((ext_vector_type(8))) short bf16x8;
typedef __attribute__((ext_vector_type(4))) float f32x4;

__device__ __align__(16) short g_q[3][2][128][128];  // [k][{Qc^T,Qs^T}][n][q]  (B-operand, K=q contiguous)
__device__ __align__(16) short g_a[3][128][256];     // [k][m][ KR row | KI row ] (A-operand, K contiguous)

static __device__ __forceinline__ short f2bf(float f) {
  unsigned u = __float_as_uint(f);
  unsigned r = (u + 0x7fffu + ((u >> 16) & 1u)) >> 16;  // RNE
  return (short)r;
}

static __device__ __forceinline__ f32x4 mfma16(bf16x8 a, bf16x8 b, f32x4 c) {
  return __builtin_amdgcn_mfma_f32_16x16x32_bf16(a, b, c, 0, 0, 0);
}

// ---------------- constant-matrix init (runs every launch; deterministic) ----------------
__global__ __launch_bounds__(256) void const_init_kernel() {
  __shared__ float qc[128], qs[128], hr[128], hf[128];
  int k = blockIdx.x >> 4;        // 3 k x 16 slices
  int slice = blockIdx.x & 15;
  int nk = 32 >> k;
  int t = threadIdx.x;
  if (t < 128) {
    const float C = 6.2831853071795864769f / 128.f;
    float ac = 1.f, as = 0.f;
    for (int j = 1; j < nk; ++j) {
      int md = (j * t) & 127;                 // exact periodic reduction
      float ang = C * (float)md;
      ac += 2.f * cosf(ang);
      as += 2.f * sinf(ang);
    }
    qc[t] = ac * (1.f / 128.f);
    qs[t] = as * (1.f / 128.f);
    float hc = 0.f, hs = 0.f;
    for (int i = 0; i < nk; ++i) {
      int md = (i * t) & 127; float ang = C * (float)md;
      hc += cosf(ang); hs += sinf(ang);
    }
    for (int i = 64; i < 128; ++i) {
      int md = (i * t) & 127; float ang = C * (float)md;
      hc += cosf(ang); hs += sinf(ang);
    }
    hr[t] = hc * (1.f / 128.f);
    hf[t] = hs * (1.f / 128.f);
  }
  __syncthreads();
  for (int e = t; e < 2048; e += 256) {       // g_q: 2*128*128 = 32768 entries / 16 slices
    int idx = slice * 2048 + e;
    int mat = idx >> 14, r = (idx >> 7) & 127, c = idx & 127;
    int d = (c - r) & 127;
    g_q[k][mat][r][c] = f2bf(mat ? qs[d] : qc[d]);
  }
  for (int e = t; e < 2048; e += 256) {       // g_a: 128*256 = 32768 entries / 16 slices
    int idx = slice * 2048 + e;
    int m = idx >> 8, c = idx & 255;
    int d = (m - (c & 127)) & 127;
    g_a[k][m][c] = f2bf((c < 128) ? hr[d] : hf[d]);
  }
}

// ---------------- gate coefficient planes into d_ws (unchanged, verified) ----------------
__global__ __launch_bounds__(256) void gates_kernel(
    const float* __restrict__ x, const float* __restrict__ Wg,
    const float* __restrict__ Bg, float* __restrict__ coef) {
  int blk = blockIdx.x;
  int b = blk >> 6;
  int tile = blk & 63;
  int m = ((tile >> 3) << 4) + (threadIdx.x >> 4);
  int n = ((tile & 7) << 4) + (threadIdx.x & 15);
  float a0 = 0.f, a1 = 0.f, a2 = 0.f;
  const float* xb = x + (size_t)b * NCHN * NPIX;
  for (int c = 0; c < NCHN; ++c) {
    const float* xc = xb + (size_t)c * NPIX;
    const float* wc = Wg + c * 9;
    #pragma unroll
    for (int dh = -1; dh <= 1; ++dh) {
      int gm = m + dh;
      bool vm = (unsigned)gm < 128u;
      #pragma unroll
      for (int dw = -1; dw <= 1; ++dw) {
        int gn = n + dw;
        float xv = (vm && (unsigned)gn < 128u) ? xc[gm * 128 + gn] : 0.f;
        int tap = (dh + 1) * 3 + (dw + 1);
        a0 = fmaf(xv, wc[tap], a0);
        a1 = fmaf(xv, wc[2304 + tap], a1);
        a2 = fmaf(xv, wc[4608 + tap], a2);
      }
    }
  }
  a0 += Bg[0]; a1 += Bg[1]; a2 += Bg[2];
  float g1 = 2.f / (1.f + expf(-a0));
  float g2 = 2.f / (1.f + expf(-a1));
  float g3 = 2.f / (1.f + expf(-a2));
  int pix = b * NPIX + m * 128 + n;
  coef[pix]          = g1;
  coef[131072 + pix] = g2 - g1;
  coef[262144 + pix] = g3 - g2;
  coef[393216 + pix] = 1.f - g3;
}

// ---------------- MFMA spectral kernel: one block per (b,c) image ----------------
__global__ __launch_bounds__(512, 4) void freq_mfma_kernel(
    const float* __restrict__ x, const float* __restrict__ coef,
    float* __restrict__ out) {
  __shared__ __align__(16) short Xs[128 * 128];  // bf16 X [p][q], XOR-swizzled rows (256B)
  __shared__ __align__(16) short Ys[64 * 256];   // bf16 [n_loc][ Y1T p | Y2T p ], swizzled (512B rows)
  char* XsB = reinterpret_cast<char*>(Xs);
  char* YsB = reinterpret_cast<char*>(Ys);
  int t = threadIdx.x;
  int img = blockIdx.x;
  int b = img >> 8;
  const float* xg = x + (size_t)img * NPIX;

  {  // load X -> bf16 swizzled LDS
    int row = t >> 2, c0 = (t & 3) * 32;
    const float4* src = reinterpret_cast<const float4*>(xg + row * 128 + c0);
    int sw = (row & 7) << 4;
    #pragma unroll
    for (int i = 0; i < 8; ++i) {
      float4 v = src[i];
      short4 s;
      s.x = f2bf(v.x); s.y = f2bf(v.y); s.z = f2bf(v.z); s.w = f2bf(v.w);
      int byte = row * 256 + (((c0 + i * 4) * 2) ^ sw);
      *reinterpret_cast<short4*>(XsB + byte) = s;
    }
  }
  int lane = t & 63, w = t >> 6;
  int wm = w >> 2, wn = w & 3;          // wave grid: 2 (M) x 4 (N)
  int l15 = lane & 15, l4 = lane >> 4;
  __syncthreads();

  const f32x4 zero = {0.f, 0.f, 0.f, 0.f};

  for (int half = 0; half < 2; ++half) {
    int ng = half * 64 + wn * 16 + l15;   // global width col for this lane
    int nloc = wn * 16 + l15;
    int swn = (nloc & 7) << 4;
    f32x4 oacc[4];
    {  // init: g1 * x  (exact f32 x re-read, L2-hot)
      const float* c0p = coef + (size_t)b * NPIX;
      #pragma unroll
      for (int mt = 0; mt < 4; ++mt) {
        int m0 = (wm * 4 + mt) * 16 + l4 * 4;
        #pragma unroll
        for (int r = 0; r < 4; ++r) {
          int pix = (m0 + r) * 128 + ng;
          oacc[mt][r] = c0p[pix] * xg[pix];
        }
      }
    }
    for (int k = 0; k < 3; ++k) {
      // ---- stage 1: Y1 = X*Qc, Y2 = X*Qs (shared A-frags) ----
      f32x4 acc1[4] = {zero, zero, zero, zero};
      f32x4 acc2[4] = {zero, zero, zero, zero};
      #pragma unroll
      for (int ks = 0; ks < 4; ++ks) {
        int koff = ks * 32 + l4 * 8;
        bf16x8 b1 = *reinterpret_cast<const bf16x8*>(&g_q[k][0][ng][koff]);
        bf16x8 b2 = *reinterpret_cast<const bf16x8*>(&g_q[k][1][ng][koff]);
        #pragma unroll
        for (int mt = 0; mt < 4; ++mt) {
          int prow = (wm * 4 + mt) * 16 + l15;
          int byte = prow * 256 + ((koff * 2) ^ ((prow & 7) << 4));
          bf16x8 a = *reinterpret_cast<const bf16x8*>(XsB + byte);
          acc1[mt] = mfma16(a, b1, acc1[mt]);
          acc2[mt] = mfma16(a, b2, acc2[mt]);
        }
      }
      __syncthreads();  // prior stage-2 readers of Ys are done
      #pragma unroll
      for (int mt = 0; mt < 4; ++mt) {  // write Y^T tiles (C-frag rows are contiguous p)
        int p0 = (wm * 4 + mt) * 16 + l4 * 4;
        short4 s1, s2;
        s1.x = f2bf(acc1[mt][0]); s1.y = f2bf(acc1[mt][1]);
        s1.z = f2bf(acc1[mt][2]); s1.w = f2bf(acc1[mt][3]);
        s2.x = f2bf(acc2[mt][0]); s2.y = f2bf(acc2[mt][1]);
        s2.z = f2bf(acc2[mt][2]); s2.w = f2bf(acc2[mt][3]);
        *reinterpret_cast<short4*>(YsB + nloc * 512 + ((p0 * 2) ^ swn)) = s1;
        *reinterpret_cast<short4*>(YsB + nloc * 512 + (((128 + p0) * 2) ^ swn)) = s2;
      }
      __syncthreads();
      // ---- stage 2: L = [KR|KI] * [Y1T;Y2T], K=256 ----
      f32x4 acc[4] = {zero, zero, zero, zero};
      #pragma unroll
      for (int ks = 0; ks < 8; ++ks) {
        int koff = ks * 32 + l4 * 8;
        bf16x8 bb = *reinterpret_cast<const bf16x8*>(
            YsB + nloc * 512 + ((koff * 2) ^ swn));
        #pragma unroll
        for (int mt = 0; mt < 4; ++mt) {
          int mrow = (wm * 4 + mt) * 16 + l15;
          bf16x8 aa = *reinterpret_cast<const bf16x8*>(&g_a[k][mrow][koff]);
          acc[mt] = mfma16(aa, bb, acc[mt]);
        }
      }
      // ---- fold with coef plane k+1 ----
      const float* cfp = coef + (size_t)(k + 1) * 131072 + (size_t)b * NPIX;
      #pragma unroll
      for (int mt = 0; mt < 4; ++mt) {
        int m0 = (wm * 4 + mt) * 16 + l4 * 4;
        #pragma unroll
        for (int r = 0; r < 4; ++r)
          oacc[mt][r] = fmaf(cfp[(m0 + r) * 128 + ng], acc[mt][r], oacc[mt][r]);
      }
    }
    float* og = out + (size_t)img * NPIX;
    #pragma unroll
    for (int mt = 0; mt < 4; ++mt) {
      int m0 = (wm * 4 + mt) * 16 + l4 * 4;
      #pragma unroll
      for (int r = 0; r < 4; ++r)
        og[(m0 + r) * 128 + ng] = oacc[mt][r];
    }
  }
}

extern "C" void kernel_launch(void* const* d_in, const int* in_sizes, int n_in,
                              void* d_out, int out_size, void* d_ws, size_t ws_size,
                              hipStream_t stream) {
  const float* x  = (const float*)d_in[0];
  const float* Wg = (const float*)d_in[1];
  const float* Bg = (const float*)d_in[2];
  float* out  = (float*)d_out;
  float* coef = (float*)d_ws;   // 4 planes * 8 * 16384 * 4B = 2 MiB
  const_init_kernel<<<48, 256, 0, stream>>>();
  gates_kernel<<<512, 256, 0, stream>>>(x, Wg, Bg, coef);
  freq_mfma_kernel<<<2048, 512, 0, stream>>>(x, coef, out);
}